// Round 4
// baseline (199.657 us; speedup 1.0000x reference)
//
#include <hip/hip_runtime.h>

#define SS 2048
#define EE 1024
#define NH 16
#define DH 64
#define NR 128    // max stored segment rows (true count ~Binomial(2048,1/32), mean 64)

// ---- workspace layout (bytes) ----
// 0      : float vtot[1024]              (4 KB)
// 4096   : float A[1024]   (atomic)      } memset 8 KB
// 8192   : float Bh[16]    (atomic)      }
// 16384  : float xpart[64][1024]         (256 KB)
// 278528 : float Q[NR*1024]; K[...]; V[...]

__device__ __forceinline__ void fma4v(float4& a, const float4 xv,
                                      const float4 w0, const float4 w1,
                                      const float4 w2, const float4 w3) {
    a.x += xv.x * w0.x + xv.y * w1.x + xv.z * w2.x + xv.w * w3.x;
    a.y += xv.x * w0.y + xv.y * w1.y + xv.z * w2.y + xv.w * w3.y;
    a.z += xv.x * w0.z + xv.y * w1.z + xv.z * w2.z + xv.w * w3.z;
    a.w += xv.x * w0.w + xv.y * w1.w + xv.z * w2.w + xv.w * w3.w;
}

__device__ __forceinline__ void lgkm_wait() {
    asm volatile("s_waitcnt lgkmcnt(0)" ::: "memory");
}

// Block-uniform segment bounds via redundant in-block scan of seg[2048] (8 KB,
// L2-resident after first block). Returns (lo, hi_excl). 256-thread blocks.
__device__ __forceinline__ int2 seg_bounds(const int* __restrict__ seg,
                                           const int* __restrict__ pos) {
    __shared__ int sb[8];
    int t = threadIdx.x;
    int g = seg[pos[0]];
    int lomin = SS, himax = 0;
    const int4* s4 = (const int4*)seg;
#pragma unroll
    for (int i = t; i < SS / 4; i += 256) {
        int4 v = s4[i];
        int b = i * 4;
        if (v.x == g) { lomin = min(lomin, b);     himax = max(himax, b + 1); }
        if (v.y == g) { lomin = min(lomin, b + 1); himax = max(himax, b + 2); }
        if (v.z == g) { lomin = min(lomin, b + 2); himax = max(himax, b + 3); }
        if (v.w == g) { lomin = min(lomin, b + 3); himax = max(himax, b + 4); }
    }
    for (int o = 32; o; o >>= 1) {
        lomin = min(lomin, __shfl_xor(lomin, o, 64));
        himax = max(himax, __shfl_xor(himax, o, 64));
    }
    if ((t & 63) == 0) { sb[t >> 6] = lomin; sb[4 + (t >> 6)] = himax; }
    __syncthreads();
    return make_int2(min(min(sb[0], sb[1]), min(sb[2], sb[3])),
                     max(max(sb[4], sb[5]), max(sb[6], sb[7])));
}

// D1: z==0 -> x column-sum partials (64 blocks); z==1..3 -> Q/K/V projection.
// Proj block = 4 rows x 256 cols. x rows staged in LDS once (coalesced);
// inner loop streams ONLY W through VMEM (float4, 1KB/wave-instr), x via
// broadcast ds_read_b128. unroll 4 -> 16 W loads (16KB/wave) in flight.
__global__ void __launch_bounds__(256, 1) k_d1(
    const float* __restrict__ x, const int* __restrict__ seg,
    const int* __restrict__ pos,
    const float* __restrict__ Wq, const float* __restrict__ bq,
    const float* __restrict__ Wk, const float* __restrict__ bk,
    const float* __restrict__ Wv, const float* __restrict__ bv,
    float* __restrict__ xpart,
    float* __restrict__ Q, float* __restrict__ K, float* __restrict__ V,
    int nmax) {
    __shared__ float lds[4096];          // 16 KB: x-stage, then reduce (aliased)
    const int t = threadIdx.x, wv = t >> 6, lane = t & 63;

    if (blockIdx.z == 0) {               // xpart: 64 blocks x 32 rows
        int xb = blockIdx.y * 4 + blockIdx.x;
        if (xb >= 64) return;
        const float4* x4 = (const float4*)x + (size_t)(xb * 32) * 256 + t;
        float4 a = make_float4(0.f, 0.f, 0.f, 0.f);
#pragma unroll 8
        for (int r = 0; r < 32; ++r) {
            float4 v = x4[(size_t)r * 256];
            a.x += v.x; a.y += v.y; a.z += v.z; a.w += v.w;
        }
        ((float4*)(xpart + (size_t)xb * EE))[t] = a;
        return;
    }

    int2 bnd = seg_bounds(seg, pos);
    int lo = bnd.x;
    int nc = bnd.y - lo; if (nc > nmax) nc = nmax; if (nc < 1) nc = 1;
    int r0 = blockIdx.y * 4;
    if (r0 >= nc) return;
    int mat = blockIdx.z - 1;
    const float* W  = mat == 0 ? Wq : mat == 1 ? Wk : Wv;
    const float* bb = mat == 0 ? bq : mat == 1 ? bk : bv;
    float* dst      = mat == 0 ? Q  : mat == 1 ? K  : V;
    int ct = blockIdx.x;
    int e0 = ct * 256 + lane * 4;

    // ---- stage 4 x-rows (clamped) into LDS: wave wv stages row wv ----
    float (*xs)[1024] = (float(*)[1024])lds;
    int rw = r0 + wv; if (rw >= nc) rw = nc - 1;         // clamp; discarded
    {
        const float4* src = (const float4*)(x + (size_t)(lo + rw) * EE);
        float4* dstl = (float4*)&xs[wv][0];
#pragma unroll
        for (int i = 0; i < 4; ++i)
            dstl[i * 64 + lane] = src[i * 64 + lane];
    }
    __syncthreads();

    int kb = wv * 256;                   // this wave's K-chunk
    const float* Wp = W + (size_t)kb * EE + e0;
    float4 a0 = make_float4(0.f, 0.f, 0.f, 0.f);
    float4 a1 = a0, a2 = a0, a3 = a0;
#pragma unroll 4
    for (int c = 0; c < 256; c += 4) {
        float4 w0 = *(const float4*)(Wp + (size_t)(c + 0) * EE);
        float4 w1 = *(const float4*)(Wp + (size_t)(c + 1) * EE);
        float4 w2 = *(const float4*)(Wp + (size_t)(c + 2) * EE);
        float4 w3 = *(const float4*)(Wp + (size_t)(c + 3) * EE);
        float4 xv0 = *(const float4*)&xs[0][kb + c];     // broadcast ds_read
        float4 xv1 = *(const float4*)&xs[1][kb + c];
        float4 xv2 = *(const float4*)&xs[2][kb + c];
        float4 xv3 = *(const float4*)&xs[3][kb + c];
        fma4v(a0, xv0, w0, w1, w2, w3);
        fma4v(a1, xv1, w0, w1, w2, w3);
        fma4v(a2, xv2, w0, w1, w2, w3);
        fma4v(a3, xv3, w0, w1, w2, w3);
    }
    __syncthreads();                     // x-stage dead; reuse lds as reduce buf

    *(float4*)(lds + ((wv << 2) + 0) * 256 + (lane << 2)) = a0;
    *(float4*)(lds + ((wv << 2) + 1) * 256 + (lane << 2)) = a1;
    *(float4*)(lds + ((wv << 2) + 2) * 256 + (lane << 2)) = a2;
    *(float4*)(lds + ((wv << 2) + 3) * 256 + (lane << 2)) = a3;
    __syncthreads();
    // reduce 4 K-chunk partials: thread -> (row=wv, col quad=lane*4)
    int oc = lane << 2;
    float4 s0 = *(float4*)(lds + (0 * 4 + wv) * 256 + oc);
    float4 s1 = *(float4*)(lds + (1 * 4 + wv) * 256 + oc);
    float4 s2 = *(float4*)(lds + (2 * 4 + wv) * 256 + oc);
    float4 s3 = *(float4*)(lds + (3 * 4 + wv) * 256 + oc);
    float4 bbv = *(const float4*)(bb + ct * 256 + oc);
    float4 s;
    s.x = s0.x + s1.x + s2.x + s3.x + bbv.x;
    s.y = s0.y + s1.y + s2.y + s3.y + bbv.y;
    s.z = s0.z + s1.z + s2.z + s3.z + bbv.z;
    s.w = s0.w + s1.w + s2.w + s3.w + bbv.w;
    int gr = r0 + wv;
    if (gr < nc)
        *(float4*)(dst + (size_t)gr * EE + ct * 256 + oc) = s;
}

// D2: blocks 0-3 -> vtot = (xsum @ Wv) + SS*bv (xpart reduced in-LDS);
//     blocks 4+  -> attention, one wave per (row r, head h), A/Bh atomics.
__global__ void __launch_bounds__(256, 4) k_d2(
    const int* __restrict__ seg, const int* __restrict__ pos,
    const float* __restrict__ Wv, const float* __restrict__ bv,
    const float* __restrict__ xpart,
    const float* __restrict__ Q, const float* __restrict__ K,
    const float* __restrict__ V,
    float* __restrict__ vtot, float* __restrict__ A, float* __restrict__ Bh,
    int nmax) {
    __shared__ float lds[2048];
    const int t = threadIdx.x, wv = t >> 6, lane = t & 63;
    const int bid = blockIdx.x, gb = gridDim.x;

    if (bid < 4) {                       // vtot GEMV
        float4 a = make_float4(0.f, 0.f, 0.f, 0.f);
        const float4* xp4 = (const float4*)xpart + t;
#pragma unroll 8
        for (int b = 0; b < 64; ++b) {
            float4 v = xp4[(size_t)b * 256];
            a.x += v.x; a.y += v.y; a.z += v.z; a.w += v.w;
        }
        ((float4*)lds)[t] = a;           // xsum in lds[0..1023]
        __syncthreads();
        int ct = bid;
        int e0 = ct * 256 + lane * 4;
        const float* Wp = Wv + (size_t)(wv * 256) * EE + e0;
        const float* xs = lds + wv * 256;
        float4 acc = make_float4(0.f, 0.f, 0.f, 0.f);
#pragma unroll 2
        for (int c = 0; c < 256; c += 4) {
            float4 w0 = *(const float4*)(Wp + (size_t)(c + 0) * EE);
            float4 w1 = *(const float4*)(Wp + (size_t)(c + 1) * EE);
            float4 w2 = *(const float4*)(Wp + (size_t)(c + 2) * EE);
            float4 w3 = *(const float4*)(Wp + (size_t)(c + 3) * EE);
            float4 xv = *(const float4*)(xs + c);
            fma4v(acc, xv, w0, w1, w2, w3);
        }
        *(float4*)(lds + 1024 + wv * 256 + lane * 4) = acc;
        __syncthreads();
        if (t < 64) {
            int oc = t * 4;
            float4 s0 = *(float4*)(lds + 1024 + 0 * 256 + oc);
            float4 s1 = *(float4*)(lds + 1024 + 1 * 256 + oc);
            float4 s2 = *(float4*)(lds + 1024 + 2 * 256 + oc);
            float4 s3 = *(float4*)(lds + 1024 + 3 * 256 + oc);
            float4 bvv = *(const float4*)(bv + ct * 256 + oc);
            float4 s;
            s.x = s0.x + s1.x + s2.x + s3.x + bvv.x * (float)SS;
            s.y = s0.y + s1.y + s2.y + s3.y + bvv.y * (float)SS;
            s.z = s0.z + s1.z + s2.z + s3.z + bvv.z * (float)SS;
            s.w = s0.w + s1.w + s2.w + s3.w + bvv.w * (float)SS;
            *(float4*)(vtot + ct * 256 + oc) = s;
        }
        return;
    }

    int2 bnd = seg_bounds(seg, pos);
    int nc = bnd.y - bnd.x; if (nc > nmax) nc = nmax; if (nc < 1) nc = 1;
    int nit = nc * NH;
    float* ql = lds + wv * 512;          // per-wave slice: 64 q + 128 sbuf
    float* sb = ql + 64;
    for (int it = (bid - 4) * 4 + wv; it < nit; it += (gb - 4) * 4) {
        int r = it >> 4, h = it & 15;
        ql[lane] = Q[(size_t)r * EE + h * DH + lane];
        lgkm_wait();                     // cross-lane LDS visibility (same wave)
        const float4* q4 = (const float4*)ql;
        float m = 0.f;                   // out-of-seg scores are 0 -> m >= 0
        for (int j = lane; j < nc; j += 64) {
            const float4* kr = (const float4*)(K + (size_t)j * EE + h * DH);
            float s = 0.f;
#pragma unroll 4
            for (int d = 0; d < DH / 4; ++d) {
                float4 kv = kr[d];
                float4 qv = q4[d];
                s += qv.x * kv.x + qv.y * kv.y + qv.z * kv.z + qv.w * kv.w;
            }
            sb[j] = s;
            m = fmaxf(m, s);
        }
        for (int o = 32; o; o >>= 1) m = fmaxf(m, __shfl_xor(m, o, 64));
        float dl = 0.f;
        for (int j = lane; j < nc; j += 64) {
            float wgt = __expf(sb[j] - m);
            sb[j] = wgt;
            dl += wgt;
        }
        for (int o = 32; o; o >>= 1) dl += __shfl_xor(dl, o, 64);
        float em = __expf(-m);
        float denom = dl + (float)(SS - nc) * em;
        lgkm_wait();                     // sb written cross-lane before PV reads
        float acc = 0.f, vs = 0.f;
        const float* Vp = V + h * DH + lane;
        int j = 0;
        for (; j + 4 <= nc; j += 4) {
            float4 wq = *(const float4*)(sb + j);
            float v0 = Vp[(size_t)(j + 0) * EE];
            float v1 = Vp[(size_t)(j + 1) * EE];
            float v2 = Vp[(size_t)(j + 2) * EE];
            float v3 = Vp[(size_t)(j + 3) * EE];
            acc += wq.x * v0 + wq.y * v1 + wq.z * v2 + wq.w * v3;
            vs  += v0 + v1 + v2 + v3;
        }
        for (; j < nc; ++j) {
            float v0 = Vp[(size_t)j * EE];
            acc += sb[j] * v0;
            vs  += v0;
        }
        atomicAdd(&A[h * DH + lane], (acc - vs * em) / denom);
        if (lane == 0) atomicAdd(&Bh[h], em / denom);
    }
}

// D3: out = bo + ((A + vtot*Bh) @ Wo) / nc.  4 blocks x 256-col stripes.
__global__ void __launch_bounds__(256, 2) k_d3(
    const int* __restrict__ seg, const int* __restrict__ pos,
    const float* __restrict__ Wo, const float* __restrict__ bo,
    const float* __restrict__ vtot, const float* __restrict__ A,
    const float* __restrict__ Bh, int nmax, float* __restrict__ out) {
    __shared__ float lds[2048];
    const int t = threadIdx.x, wv = t >> 6, lane = t & 63;
    int2 bnd = seg_bounds(seg, pos);
    int nc = bnd.y - bnd.x; if (nc > nmax) nc = nmax; if (nc < 1) nc = 1;
    {   // outsum[c] = A[c] + vtot[c]*Bh[c>>6] -> lds[0..1023]
        float4 av = ((const float4*)A)[t];
        float4 vv = ((const float4*)vtot)[t];
        float bh = Bh[t >> 4];
        float4 o4;
        o4.x = av.x + vv.x * bh;
        o4.y = av.y + vv.y * bh;
        o4.z = av.z + vv.z * bh;
        o4.w = av.w + vv.w * bh;
        ((float4*)lds)[t] = o4;
    }
    __syncthreads();
    int ct = blockIdx.x;
    int e0 = ct * 256 + lane * 4;
    const float* Wp = Wo + (size_t)(wv * 256) * EE + e0;
    const float* osp = lds + wv * 256;
    float4 a = make_float4(0.f, 0.f, 0.f, 0.f);
#pragma unroll 2
    for (int c = 0; c < 256; c += 4) {
        float4 w0 = *(const float4*)(Wp + (size_t)(c + 0) * EE);
        float4 w1 = *(const float4*)(Wp + (size_t)(c + 1) * EE);
        float4 w2 = *(const float4*)(Wp + (size_t)(c + 2) * EE);
        float4 w3 = *(const float4*)(Wp + (size_t)(c + 3) * EE);
        float4 ov = *(const float4*)(osp + c);
        fma4v(a, ov, w0, w1, w2, w3);
    }
    *(float4*)(lds + 1024 + wv * 256 + lane * 4) = a;
    __syncthreads();
    if (t < 64) {
        int oc = t * 4;
        float4 s0 = *(float4*)(lds + 1024 + 0 * 256 + oc);
        float4 s1 = *(float4*)(lds + 1024 + 1 * 256 + oc);
        float4 s2 = *(float4*)(lds + 1024 + 2 * 256 + oc);
        float4 s3 = *(float4*)(lds + 1024 + 3 * 256 + oc);
        float inv = 1.f / (float)nc;
        float4 bov = *(const float4*)(bo + ct * 256 + oc);
        float4 o;
        o.x = bov.x + (s0.x + s1.x + s2.x + s3.x) * inv;
        o.y = bov.y + (s0.y + s1.y + s2.y + s3.y) * inv;
        o.z = bov.z + (s0.z + s1.z + s2.z + s3.z) * inv;
        o.w = bov.w + (s0.w + s1.w + s2.w + s3.w) * inv;
        *(float4*)(out + ct * 256 + oc) = o;
    }
}

extern "C" void kernel_launch(void* const* d_in, const int* in_sizes, int n_in,
                              void* d_out, int out_size, void* d_ws, size_t ws_size,
                              hipStream_t stream) {
    const float* x  = (const float*)d_in[0];
    const int* seg  = (const int*)d_in[1];
    const int* pos  = (const int*)d_in[2];
    const float* Wq = (const float*)d_in[3];
    const float* bq = (const float*)d_in[4];
    const float* Wk = (const float*)d_in[5];
    const float* bk = (const float*)d_in[6];
    const float* Wv = (const float*)d_in[7];
    const float* bv = (const float*)d_in[8];
    const float* Wo = (const float*)d_in[9];
    const float* bo = (const float*)d_in[10];
    float* out = (float*)d_out;

    char* w = (char*)d_ws;
    float* vtot  = (float*)(w + 0);
    float* A     = (float*)(w + 4096);
    float* Bh    = (float*)(w + 8192);
    float* xpart = (float*)(w + 16384);

    size_t base = 16384 + 64 * EE * sizeof(float);     // 278528
    size_t avail = (ws_size > base) ? ws_size - base : 0;
    int nmax = (int)(avail / (3ull * EE * sizeof(float)));
    if (nmax > NR) nmax = NR;
    if (nmax < 1) nmax = 1;
    float* Q = (float*)(w + base);
    float* K = Q + (size_t)nmax * EE;
    float* V = K + (size_t)nmax * EE;

    int RT = (nmax + 3) / 4;
    int RY = RT > 16 ? RT : 16;          // y-extent must cover 64 xpart blocks

    hipMemsetAsync(w + 4096, 0, 8192, stream);         // A, Bh
    k_d1<<<dim3(4, RY, 4), 256, 0, stream>>>(
        x, seg, pos, Wq, bq, Wk, bk, Wv, bv, xpart, Q, K, V, nmax);
    k_d2<<<260, 256, 0, stream>>>(
        seg, pos, Wv, bv, xpart, Q, K, V, vtot, A, Bh, nmax);
    k_d3<<<4, 256, 0, stream>>>(seg, pos, Wo, bo, vtot, A, Bh, nmax, out);
}

// Round 5
// 157.254 us; speedup vs baseline: 1.2696x; 1.2696x over previous
//
#include <hip/hip_runtime.h>

#define SS 2048
#define EE 1024
#define NH 16
#define DH 64
#define NR 128    // max stored segment rows (true count ~Binomial(2048,1/32), mean 64)

// ---- workspace layout (bytes) ----
// 0      : float vtot[1024]              (4 KB)
// 4096   : float A[1024]   (atomic)      } memset 8 KB
// 8192   : float Bh[16]    (atomic)      }
// 16384  : float xpart[64][1024]         (256 KB)
// 278528 : float Q[NR*1024]; K[...]; V[...]

__device__ __forceinline__ void fma4v(float4& a, const float4 xv,
                                      const float4 w0, const float4 w1,
                                      const float4 w2, const float4 w3) {
    a.x += xv.x * w0.x + xv.y * w1.x + xv.z * w2.x + xv.w * w3.x;
    a.y += xv.x * w0.y + xv.y * w1.y + xv.z * w2.y + xv.w * w3.y;
    a.z += xv.x * w0.z + xv.y * w1.z + xv.z * w2.z + xv.w * w3.z;
    a.w += xv.x * w0.w + xv.y * w1.w + xv.z * w2.w + xv.w * w3.w;
}

__device__ __forceinline__ void lgkm_wait() {
    asm volatile("s_waitcnt lgkmcnt(0)" ::: "memory");
}

// Block-uniform segment bounds via redundant in-block scan of seg[2048] (8 KB,
// L2-resident after first block). Returns (lo, hi_excl). 256-thread blocks.
__device__ __forceinline__ int2 seg_bounds(const int* __restrict__ seg,
                                           const int* __restrict__ pos) {
    __shared__ int sb[8];
    int t = threadIdx.x;
    int g = seg[pos[0]];
    int lomin = SS, himax = 0;
    const int4* s4 = (const int4*)seg;
#pragma unroll
    for (int i = t; i < SS / 4; i += 256) {
        int4 v = s4[i];
        int b = i * 4;
        if (v.x == g) { lomin = min(lomin, b);     himax = max(himax, b + 1); }
        if (v.y == g) { lomin = min(lomin, b + 1); himax = max(himax, b + 2); }
        if (v.z == g) { lomin = min(lomin, b + 2); himax = max(himax, b + 3); }
        if (v.w == g) { lomin = min(lomin, b + 3); himax = max(himax, b + 4); }
    }
    for (int o = 32; o; o >>= 1) {
        lomin = min(lomin, __shfl_xor(lomin, o, 64));
        himax = max(himax, __shfl_xor(himax, o, 64));
    }
    if ((t & 63) == 0) { sb[t >> 6] = lomin; sb[4 + (t >> 6)] = himax; }
    __syncthreads();
    return make_int2(min(min(sb[0], sb[1]), min(sb[2], sb[3])),
                     max(max(sb[4], sb[5]), max(sb[6], sb[7])));
}

// D1: z==0 -> x column-sum partials (64 blocks); z==1..3 -> Q/K/V projection.
// Proj block = 4 rows x 64 cols; wave wv = K-chunk of 256, lane = ONE col.
// Inner iter: 1 coalesced global_load_dword (W) + 4 LDS broadcasts + 4 FMAs.
// 768 live blocks -> 12 waves/CU; unroll 8 -> 8 loads in flight per wave
// (~24 KB/CU outstanding == Little's law for ~50 B/cyc/CU of L2 BW).
__global__ void __launch_bounds__(256, 4) k_d1(
    const float* __restrict__ x, const int* __restrict__ seg,
    const int* __restrict__ pos,
    const float* __restrict__ Wq, const float* __restrict__ bq,
    const float* __restrict__ Wk, const float* __restrict__ bk,
    const float* __restrict__ Wv, const float* __restrict__ bv,
    float* __restrict__ xpart,
    float* __restrict__ Q, float* __restrict__ K, float* __restrict__ V,
    int nmax) {
    __shared__ float lds[4096];          // 16 KB: xs[4][1024]; red aliased after
    const int t = threadIdx.x, wv = t >> 6, lane = t & 63;

    if (blockIdx.z == 0) {               // xpart: 64 blocks x 32 rows
        int xb = blockIdx.y * 16 + blockIdx.x;
        if (xb >= 64) return;
        const float4* x4 = (const float4*)x + (size_t)(xb * 32) * 256 + t;
        float4 a = make_float4(0.f, 0.f, 0.f, 0.f);
#pragma unroll 8
        for (int r = 0; r < 32; ++r) {
            float4 v = x4[(size_t)r * 256];
            a.x += v.x; a.y += v.y; a.z += v.z; a.w += v.w;
        }
        ((float4*)(xpart + (size_t)xb * EE))[t] = a;
        return;
    }

    int2 bnd = seg_bounds(seg, pos);
    int lo = bnd.x;
    int nc = bnd.y - lo; if (nc > nmax) nc = nmax; if (nc < 1) nc = 1;
    int r0 = blockIdx.y * 4;
    if (r0 >= nc) return;
    int mat = blockIdx.z - 1;
    const float* W  = mat == 0 ? Wq : mat == 1 ? Wk : Wv;
    const float* bb = mat == 0 ? bq : mat == 1 ? bk : bv;
    float* dst      = mat == 0 ? Q  : mat == 1 ? K  : V;
    int e = blockIdx.x * 64 + lane;      // this lane's single output column

    // ---- stage 4 x-rows (clamped) into LDS: wave wv stages row wv ----
    float (*xs)[1024] = (float(*)[1024])lds;
    int rw = r0 + wv; if (rw >= nc) rw = nc - 1;         // clamp; discarded
    {
        const float4* src = (const float4*)(x + (size_t)(lo + rw) * EE);
        float4* dl = (float4*)&xs[wv][0];
#pragma unroll
        for (int i = 0; i < 4; ++i)
            dl[i * 64 + lane] = src[i * 64 + lane];
    }
    __syncthreads();

    const float* Wp = W + (size_t)(wv * 256) * EE + e;   // wave's K-chunk
    const float* x0 = &xs[0][wv * 256];  // broadcast LDS reads (conflict-free)
    const float* x1 = &xs[1][wv * 256];
    const float* x2 = &xs[2][wv * 256];
    const float* x3 = &xs[3][wv * 256];
    float a0 = 0.f, a1 = 0.f, a2 = 0.f, a3 = 0.f;
#pragma unroll 8
    for (int c = 0; c < 256; ++c) {
        float wj = Wp[(size_t)c * EE];
        a0 += x0[c] * wj;
        a1 += x1[c] * wj;
        a2 += x2[c] * wj;
        a3 += x3[c] * wj;
    }
    __syncthreads();                     // xs dead; reuse LDS as reduce buffer

    float* red = lds;                    // [kc][row][64]
    red[(wv * 4 + 0) * 64 + lane] = a0;
    red[(wv * 4 + 1) * 64 + lane] = a1;
    red[(wv * 4 + 2) * 64 + lane] = a2;
    red[(wv * 4 + 3) * 64 + lane] = a3;
    __syncthreads();
    // wave wv finalizes row wv: sum the 4 K-chunk partials + bias
    float s = red[(0 * 4 + wv) * 64 + lane] + red[(1 * 4 + wv) * 64 + lane]
            + red[(2 * 4 + wv) * 64 + lane] + red[(3 * 4 + wv) * 64 + lane]
            + bb[e];
    int gr = r0 + wv;
    if (gr < nc)
        dst[(size_t)gr * EE + e] = s;    // 256 B coalesced store per wave
}

// D2: blocks 0-3 -> vtot = (xsum @ Wv) + SS*bv (xpart reduced in-LDS);
//     blocks 4+  -> attention, one wave per (row r, head h), A/Bh atomics.
__global__ void __launch_bounds__(256, 4) k_d2(
    const int* __restrict__ seg, const int* __restrict__ pos,
    const float* __restrict__ Wv, const float* __restrict__ bv,
    const float* __restrict__ xpart,
    const float* __restrict__ Q, const float* __restrict__ K,
    const float* __restrict__ V,
    float* __restrict__ vtot, float* __restrict__ A, float* __restrict__ Bh,
    int nmax) {
    __shared__ float lds[2048];
    const int t = threadIdx.x, wv = t >> 6, lane = t & 63;
    const int bid = blockIdx.x, gb = gridDim.x;

    if (bid < 4) {                       // vtot GEMV
        float4 a = make_float4(0.f, 0.f, 0.f, 0.f);
        const float4* xp4 = (const float4*)xpart + t;
#pragma unroll 8
        for (int b = 0; b < 64; ++b) {
            float4 v = xp4[(size_t)b * 256];
            a.x += v.x; a.y += v.y; a.z += v.z; a.w += v.w;
        }
        ((float4*)lds)[t] = a;           // xsum in lds[0..1023]
        __syncthreads();
        int ct = bid;
        int e0 = ct * 256 + lane * 4;
        const float* Wp = Wv + (size_t)(wv * 256) * EE + e0;
        const float* xs = lds + wv * 256;
        float4 acc = make_float4(0.f, 0.f, 0.f, 0.f);
#pragma unroll 2
        for (int c = 0; c < 256; c += 4) {
            float4 w0 = *(const float4*)(Wp + (size_t)(c + 0) * EE);
            float4 w1 = *(const float4*)(Wp + (size_t)(c + 1) * EE);
            float4 w2 = *(const float4*)(Wp + (size_t)(c + 2) * EE);
            float4 w3 = *(const float4*)(Wp + (size_t)(c + 3) * EE);
            float4 xv = *(const float4*)(xs + c);
            fma4v(acc, xv, w0, w1, w2, w3);
        }
        *(float4*)(lds + 1024 + wv * 256 + lane * 4) = acc;
        __syncthreads();
        if (t < 64) {
            int oc = t * 4;
            float4 s0 = *(float4*)(lds + 1024 + 0 * 256 + oc);
            float4 s1 = *(float4*)(lds + 1024 + 1 * 256 + oc);
            float4 s2 = *(float4*)(lds + 1024 + 2 * 256 + oc);
            float4 s3 = *(float4*)(lds + 1024 + 3 * 256 + oc);
            float4 bvv = *(const float4*)(bv + ct * 256 + oc);
            float4 s;
            s.x = s0.x + s1.x + s2.x + s3.x + bvv.x * (float)SS;
            s.y = s0.y + s1.y + s2.y + s3.y + bvv.y * (float)SS;
            s.z = s0.z + s1.z + s2.z + s3.z + bvv.z * (float)SS;
            s.w = s0.w + s1.w + s2.w + s3.w + bvv.w * (float)SS;
            *(float4*)(vtot + ct * 256 + oc) = s;
        }
        return;
    }

    int2 bnd = seg_bounds(seg, pos);
    int nc = bnd.y - bnd.x; if (nc > nmax) nc = nmax; if (nc < 1) nc = 1;
    int nit = nc * NH;
    float* ql = lds + wv * 512;          // per-wave slice: 64 q + 128 sbuf
    float* sb = ql + 64;
    for (int it = (bid - 4) * 4 + wv; it < nit; it += (gb - 4) * 4) {
        int r = it >> 4, h = it & 15;
        ql[lane] = Q[(size_t)r * EE + h * DH + lane];
        lgkm_wait();                     // cross-lane LDS visibility (same wave)
        const float4* q4 = (const float4*)ql;
        float m = 0.f;                   // out-of-seg scores are 0 -> m >= 0
        for (int j = lane; j < nc; j += 64) {
            const float4* kr = (const float4*)(K + (size_t)j * EE + h * DH);
            float s = 0.f;
#pragma unroll 4
            for (int d = 0; d < DH / 4; ++d) {
                float4 kv = kr[d];
                float4 qv = q4[d];
                s += qv.x * kv.x + qv.y * kv.y + qv.z * kv.z + qv.w * kv.w;
            }
            sb[j] = s;
            m = fmaxf(m, s);
        }
        for (int o = 32; o; o >>= 1) m = fmaxf(m, __shfl_xor(m, o, 64));
        float dl = 0.f;
        for (int j = lane; j < nc; j += 64) {
            float wgt = __expf(sb[j] - m);
            sb[j] = wgt;
            dl += wgt;
        }
        for (int o = 32; o; o >>= 1) dl += __shfl_xor(dl, o, 64);
        float em = __expf(-m);
        float denom = dl + (float)(SS - nc) * em;
        lgkm_wait();                     // sb written cross-lane before PV reads
        float acc = 0.f, vs = 0.f;
        const float* Vp = V + h * DH + lane;
        int j = 0;
        for (; j + 4 <= nc; j += 4) {
            float4 wq = *(const float4*)(sb + j);
            float v0 = Vp[(size_t)(j + 0) * EE];
            float v1 = Vp[(size_t)(j + 1) * EE];
            float v2 = Vp[(size_t)(j + 2) * EE];
            float v3 = Vp[(size_t)(j + 3) * EE];
            acc += wq.x * v0 + wq.y * v1 + wq.z * v2 + wq.w * v3;
            vs  += v0 + v1 + v2 + v3;
        }
        for (; j < nc; ++j) {
            float v0 = Vp[(size_t)j * EE];
            acc += sb[j] * v0;
            vs  += v0;
        }
        atomicAdd(&A[h * DH + lane], (acc - vs * em) / denom);
        if (lane == 0) atomicAdd(&Bh[h], em / denom);
    }
}

// D3: out = bo + ((A + vtot*Bh) @ Wo) / nc.  4 blocks x 256-col stripes.
__global__ void __launch_bounds__(256, 2) k_d3(
    const int* __restrict__ seg, const int* __restrict__ pos,
    const float* __restrict__ Wo, const float* __restrict__ bo,
    const float* __restrict__ vtot, const float* __restrict__ A,
    const float* __restrict__ Bh, int nmax, float* __restrict__ out) {
    __shared__ float lds[2048];
    const int t = threadIdx.x, wv = t >> 6, lane = t & 63;
    int2 bnd = seg_bounds(seg, pos);
    int nc = bnd.y - bnd.x; if (nc > nmax) nc = nmax; if (nc < 1) nc = 1;
    {   // outsum[c] = A[c] + vtot[c]*Bh[c>>6] -> lds[0..1023]
        float4 av = ((const float4*)A)[t];
        float4 vv = ((const float4*)vtot)[t];
        float bh = Bh[t >> 4];
        float4 o4;
        o4.x = av.x + vv.x * bh;
        o4.y = av.y + vv.y * bh;
        o4.z = av.z + vv.z * bh;
        o4.w = av.w + vv.w * bh;
        ((float4*)lds)[t] = o4;
    }
    __syncthreads();
    int ct = blockIdx.x;
    int e0 = ct * 256 + lane * 4;
    const float* Wp = Wo + (size_t)(wv * 256) * EE + e0;
    const float* osp = lds + wv * 256;
    float4 a = make_float4(0.f, 0.f, 0.f, 0.f);
#pragma unroll 2
    for (int c = 0; c < 256; c += 4) {
        float4 w0 = *(const float4*)(Wp + (size_t)(c + 0) * EE);
        float4 w1 = *(const float4*)(Wp + (size_t)(c + 1) * EE);
        float4 w2 = *(const float4*)(Wp + (size_t)(c + 2) * EE);
        float4 w3 = *(const float4*)(Wp + (size_t)(c + 3) * EE);
        float4 ov = *(const float4*)(osp + c);
        fma4v(a, ov, w0, w1, w2, w3);
    }
    *(float4*)(lds + 1024 + wv * 256 + lane * 4) = a;
    __syncthreads();
    if (t < 64) {
        int oc = t * 4;
        float4 s0 = *(float4*)(lds + 1024 + 0 * 256 + oc);
        float4 s1 = *(float4*)(lds + 1024 + 1 * 256 + oc);
        float4 s2 = *(float4*)(lds + 1024 + 2 * 256 + oc);
        float4 s3 = *(float4*)(lds + 1024 + 3 * 256 + oc);
        float inv = 1.f / (float)nc;
        float4 bov = *(const float4*)(bo + ct * 256 + oc);
        float4 o;
        o.x = bov.x + (s0.x + s1.x + s2.x + s3.x) * inv;
        o.y = bov.y + (s0.y + s1.y + s2.y + s3.y) * inv;
        o.z = bov.z + (s0.z + s1.z + s2.z + s3.z) * inv;
        o.w = bov.w + (s0.w + s1.w + s2.w + s3.w) * inv;
        *(float4*)(out + ct * 256 + oc) = o;
    }
}

extern "C" void kernel_launch(void* const* d_in, const int* in_sizes, int n_in,
                              void* d_out, int out_size, void* d_ws, size_t ws_size,
                              hipStream_t stream) {
    const float* x  = (const float*)d_in[0];
    const int* seg  = (const int*)d_in[1];
    const int* pos  = (const int*)d_in[2];
    const float* Wq = (const float*)d_in[3];
    const float* bq = (const float*)d_in[4];
    const float* Wk = (const float*)d_in[5];
    const float* bk = (const float*)d_in[6];
    const float* Wv = (const float*)d_in[7];
    const float* bv = (const float*)d_in[8];
    const float* Wo = (const float*)d_in[9];
    const float* bo = (const float*)d_in[10];
    float* out = (float*)d_out;

    char* w = (char*)d_ws;
    float* vtot  = (float*)(w + 0);
    float* A     = (float*)(w + 4096);
    float* Bh    = (float*)(w + 8192);
    float* xpart = (float*)(w + 16384);

    size_t base = 16384 + 64 * EE * sizeof(float);     // 278528
    size_t avail = (ws_size > base) ? ws_size - base : 0;
    int nmax = (int)(avail / (3ull * EE * sizeof(float)));
    if (nmax > NR) nmax = NR;
    if (nmax < 1) nmax = 1;
    float* Q = (float*)(w + base);
    float* K = Q + (size_t)nmax * EE;
    float* V = K + (size_t)nmax * EE;

    int RT = (nmax + 3) / 4;
    int RY = RT > 4 ? RT : 4;            // y*16+x must cover 64 xpart blocks

    hipMemsetAsync(w + 4096, 0, 8192, stream);         // A, Bh
    k_d1<<<dim3(16, RY, 4), 256, 0, stream>>>(
        x, seg, pos, Wq, bq, Wk, bk, Wv, bv, xpart, Q, K, V, nmax);
    k_d2<<<260, 256, 0, stream>>>(
        seg, pos, Wv, bv, xpart, Q, K, V, vtot, A, Bh, nmax);
    k_d3<<<4, 256, 0, stream>>>(seg, pos, Wo, bo, vtot, A, Bh, nmax, out);
}